// Round 4
// baseline (354.718 us; speedup 1.0000x reference)
//
#include <hip/hip_runtime.h>
#include <hip/hip_bf16.h>
#include <math.h>

#define BB   32
#define NN   64
#define NGG  100
#define NBB  128
#define NFF  256
#define NITER 3
#define KPAD 128   // NG=100 padded to MFMA K multiple

typedef _Float16 f16x8 __attribute__((ext_vector_type(8)));
typedef _Float16 f16x4 __attribute__((ext_vector_type(4)));
typedef float    f32x4 __attribute__((ext_vector_type(4)));

static __device__ __forceinline__ float fast_exp2(float x) {
    float r; asm("v_exp_f32 %0, %1" : "=v"(r) : "v"(x)); return r;
}
static __device__ __forceinline__ float fast_rcp(float x) {
    float r; asm("v_rcp_f32 %0, %1" : "=v"(r) : "v"(x)); return r;
}
// tanh(x) = 1 - 2/(e^{2x}+1). Saturates correctly for large |x|.
static __device__ __forceinline__ float fast_tanh(float x) {
    float p = fast_exp2(x * 2.8853900817779268f);
    return 1.0f - 2.0f * fast_rcp(p + 1.0f);
}

// ---------------- embed: X[b,n,:] = W_emb[Z[b,n],:] ----------------
__global__ void embed_kernel(const int* __restrict__ Z, const float* __restrict__ W_emb,
                             float* __restrict__ X) {
    int bn = blockIdx.x, t = threadIdx.x;
    X[bn * NBB + t] = W_emb[Z[bn] * NBB + t];
}

// ---------------- transpose + pad + fp16: dst[c*Kpad+k] = k<K ? src[k*NC+c] : 0 ----------------
__global__ void transpose_pad_kernel(const float* __restrict__ src, _Float16* __restrict__ dst,
                                     int K, int Kpad, int NC) {
    int idx = blockIdx.x * 256 + threadIdx.x;
    if (idx >= NC * Kpad) return;
    int c = idx / Kpad, k = idx - c * Kpad;
    dst[idx] = (k < K) ? (_Float16)src[(size_t)k * NC + c] : (_Float16)0.f;
}

// ---------------- fX = X @ Wi + bi -> fp16, rows with Z==0 zeroed ----------------
__global__ void fx_kernel(const float* __restrict__ X, const float* __restrict__ Wi,
                          const float* __restrict__ bi, const int* __restrict__ Z,
                          _Float16* __restrict__ fXh) {
    __shared__ float Xs[NBB];
    int bn = blockIdx.x, t = threadIdx.x;
    if (t < NBB) Xs[t] = X[bn * NBB + t];
    __syncthreads();
    float acc = bi[t];
    for (int k = 0; k < NBB; ++k) acc += Xs[k] * Wi[k * NFF + t];
    fXh[bn * NFF + t] = (Z[bn] > 0) ? (_Float16)acc : (_Float16)0.f;
}

// ======================= shared phase-A building block =======================
// Stage C[b,i] (fp32) -> Cs fp16 [64][128], XOR-swizzled rows, zero-pad k>=100.
static __device__ __forceinline__ void stage_C(const float* Crow_base, _Float16* Cs, int t) {
    const int r = t >> 2, q = t & 3;
    const float* Crow = Crow_base + (size_t)r * NGG;
    const int sw = (r & 7) << 3;
    #pragma unroll
    for (int m = 0; m < 8; ++m) {
        const int k = q * 32 + m * 4;
        f16x4 h = {0.f, 0.f, 0.f, 0.f};
        if (k < NGG) {
            float4 v = *(const float4*)(Crow + k);
            h[0] = (_Float16)v.x; h[1] = (_Float16)v.y;
            h[2] = (_Float16)v.z; h[3] = (_Float16)v.w;
        }
        *(f16x4*)&Cs[r * KPAD + (k ^ sw)] = h;
    }
}

// ---------------- split path: fCh[bi,j,f] = C[bi,j,:]@Wc + bc (once; pass-invariant) ----------------
__global__ __launch_bounds__(256, 3) void fc_kernel(
    const int* __restrict__ Z, const float* __restrict__ C,
    const _Float16* __restrict__ WcT, const float* __restrict__ bc,
    _Float16* __restrict__ fCh)
{
    __shared__ __align__(16) _Float16 Cs[NN * KPAD];  // 16 KB
    const int bi_ = blockIdx.x;
    const int b = bi_ >> 6, i = bi_ & 63;
    if (Z[b * NN + i] == 0) return;   // rows never read downstream

    const int t = threadIdx.x;
    const int wave = t >> 6, lane = t & 63;
    const int l15 = lane & 15, kg = lane >> 4;

    stage_C(C + (size_t)bi_ * NN * NGG, Cs, t);

    // A-frags: wave owns f-range [64*wave, 64*wave+64)
    f16x8 aw[4][4];
    float4 bcq[4];
    #pragma unroll
    for (int ct = 0; ct < 4; ++ct) {
        #pragma unroll
        for (int ks = 0; ks < 4; ++ks)
            aw[ct][ks] = *(const f16x8*)&WcT[(size_t)(wave * 64 + ct * 16 + l15) * KPAD + ks * 32 + kg * 8];
        bcq[ct] = *(const float4*)&bc[wave * 64 + ct * 16 + kg * 4];
    }
    __syncthreads();

    #pragma unroll
    for (int jt = 0; jt < 4; ++jt) {
        const int j = jt * 16 + l15;
        const int sw = (l15 & 7) << 3;
        f16x8 bfr[4];
        #pragma unroll
        for (int ks = 0; ks < 4; ++ks)
            bfr[ks] = *(const f16x8*)&Cs[j * KPAD + ((ks * 32 + kg * 8) ^ sw)];
        #pragma unroll
        for (int ct = 0; ct < 4; ++ct) {
            f32x4 acc = {bcq[ct].x, bcq[ct].y, bcq[ct].z, bcq[ct].w};
            #pragma unroll
            for (int ks = 0; ks < 4; ++ks)
                acc = __builtin_amdgcn_mfma_f32_16x16x32_f16(aw[ct][ks], bfr[ks], acc, 0, 0, 0);
            // D: col=l15 (=j_local), row=kg*4+reg (=f within ct tile)
            const int f0 = wave * 64 + ct * 16 + kg * 4;
            f16x4 o;
            o[0] = (_Float16)acc[0]; o[1] = (_Float16)acc[1];
            o[2] = (_Float16)acc[2]; o[3] = (_Float16)acc[3];
            *(f16x4*)&fCh[((size_t)bi_ * NN + j) * NFF + f0] = o;
        }
    }
}

// ---------------- split path: per-pass interact = fV=fCh⊙fXh ; pre=fV@Wf ; X += Σ tanh ----------------
__global__ __launch_bounds__(256) void interact_lite(
    const int* __restrict__ Z, const _Float16* __restrict__ fCh,
    const _Float16* __restrict__ WfT, const _Float16* __restrict__ fXh,
    float* __restrict__ X)
{
    const int bi_ = blockIdx.x;
    const int b = bi_ >> 6, i = bi_ & 63;
    if (Z[b * NN + i] == 0) return;

    const int t = threadIdx.x;
    const int wave = t >> 6, lane = t & 63;
    const int l15 = lane & 15, kg = lane >> 4;

    f16x8 bwf[2][8];
    #pragma unroll
    for (int ct = 0; ct < 2; ++ct)
        #pragma unroll
        for (int ks = 0; ks < 8; ++ks)
            bwf[ct][ks] = *(const f16x8*)&WfT[(size_t)(wave * 32 + ct * 16 + l15) * NFF + ks * 32 + kg * 8];

    float vsum0 = 0.f, vsum1 = 0.f;
    #pragma unroll
    for (int jt = 0; jt < 4; ++jt) {
        const int j = jt * 16 + l15;
        const f16x8* fcp = (const f16x8*)&fCh[((size_t)bi_ * NN + j) * NFF];
        const f16x8* fxp = (const f16x8*)&fXh[((size_t)(b * NN) + j) * NFF];
        f32x4 a0 = {0.f, 0.f, 0.f, 0.f}, a1 = {0.f, 0.f, 0.f, 0.f};
        #pragma unroll
        for (int ks = 0; ks < 8; ++ks) {
            f16x8 av = fcp[ks * 4 + kg] * fxp[ks * 4 + kg];   // v_pk_mul_f16
            a0 = __builtin_amdgcn_mfma_f32_16x16x32_f16(av, bwf[0][ks], a0, 0, 0, 0);
            a1 = __builtin_amdgcn_mfma_f32_16x16x32_f16(av, bwf[1][ks], a1, 0, 0, 0);
        }
        #pragma unroll
        for (int reg = 0; reg < 4; ++reg) {
            int j2 = jt * 16 + kg * 4 + reg;
            if (j2 != i) {
                vsum0 += fast_tanh(a0[reg]);
                vsum1 += fast_tanh(a1[reg]);
            }
        }
    }
    vsum0 += __shfl_xor(vsum0, 16); vsum0 += __shfl_xor(vsum0, 32);
    vsum1 += __shfl_xor(vsum1, 16); vsum1 += __shfl_xor(vsum1, 32);
    if (lane < 16) {
        float* Xp = X + (size_t)bi_ * NBB + wave * 32 + lane;
        Xp[0]  += vsum0;
        Xp[16] += vsum1;
    }
}

// ---------------- fused fallback: phase A (recompute fC) + phase B, all in one ----------------
__global__ __launch_bounds__(256, 3) void interact_fused(
    const int* __restrict__ Z, const float* __restrict__ C,
    const _Float16* __restrict__ WcT, const float* __restrict__ bc,
    const _Float16* __restrict__ WfT, const _Float16* __restrict__ fXh,
    float* __restrict__ X)
{
    __shared__ __align__(16) _Float16 Cs[NN * KPAD];   // 16 KB
    __shared__ __align__(16) _Float16 fVs[NN * NFF];   // 32 KB

    const int bi_ = blockIdx.x;
    const int b = bi_ >> 6, i = bi_ & 63;
    if (Z[b * NN + i] == 0) return;

    const int t = threadIdx.x;
    const int wave = t >> 6, lane = t & 63;
    const int l15 = lane & 15, kg = lane >> 4;

    stage_C(C + (size_t)bi_ * NN * NGG, Cs, t);

    f16x8 aw[4][4];
    float4 bcq[4];
    #pragma unroll
    for (int ct = 0; ct < 4; ++ct) {
        #pragma unroll
        for (int ks = 0; ks < 4; ++ks)
            aw[ct][ks] = *(const f16x8*)&WcT[(size_t)(wave * 64 + ct * 16 + l15) * KPAD + ks * 32 + kg * 8];
        bcq[ct] = *(const float4*)&bc[wave * 64 + ct * 16 + kg * 4];
    }
    __syncthreads();

    // phase A: wave owns f-cols [64w,64w+64); iterate all j tiles from LDS
    #pragma unroll
    for (int jt = 0; jt < 4; ++jt) {
        const int j = jt * 16 + l15;
        const int sw = (l15 & 7) << 3;
        f16x8 bfr[4];
        #pragma unroll
        for (int ks = 0; ks < 4; ++ks)
            bfr[ks] = *(const f16x8*)&Cs[j * KPAD + ((ks * 32 + kg * 8) ^ sw)];
        #pragma unroll
        for (int ct = 0; ct < 4; ++ct) {
            f32x4 acc = {bcq[ct].x, bcq[ct].y, bcq[ct].z, bcq[ct].w};
            #pragma unroll
            for (int ks = 0; ks < 4; ++ks)
                acc = __builtin_amdgcn_mfma_f32_16x16x32_f16(aw[ct][ks], bfr[ks], acc, 0, 0, 0);
            const int f0 = wave * 64 + ct * 16 + kg * 4;
            f16x4 fx4 = *(const f16x4*)&fXh[((size_t)(b * NN) + j) * NFF + f0];
            f16x4 o;
            o[0] = (_Float16)(acc[0] * (float)fx4[0]);
            o[1] = (_Float16)(acc[1] * (float)fx4[1]);
            o[2] = (_Float16)(acc[2] * (float)fx4[2]);
            o[3] = (_Float16)(acc[3] * (float)fx4[3]);
            *(f16x4*)&fVs[j * NFF + (f0 ^ ((j & 7) << 3))] = o;
        }
    }
    __syncthreads();

    // phase B: wave owns out-cols [32w, 32w+32)
    f16x8 bwf[2][8];
    #pragma unroll
    for (int ct = 0; ct < 2; ++ct)
        #pragma unroll
        for (int ks = 0; ks < 8; ++ks)
            bwf[ct][ks] = *(const f16x8*)&WfT[(size_t)(wave * 32 + ct * 16 + l15) * NFF + ks * 32 + kg * 8];

    float vsum0 = 0.f, vsum1 = 0.f;
    #pragma unroll
    for (int jt = 0; jt < 4; ++jt) {
        const int r = jt * 16 + l15;
        const int sw = (l15 & 7) << 3;
        f32x4 a0 = {0.f, 0.f, 0.f, 0.f}, a1 = {0.f, 0.f, 0.f, 0.f};
        #pragma unroll
        for (int ks = 0; ks < 8; ++ks) {
            f16x8 av = *(const f16x8*)&fVs[r * NFF + ((ks * 32 + kg * 8) ^ sw)];
            a0 = __builtin_amdgcn_mfma_f32_16x16x32_f16(av, bwf[0][ks], a0, 0, 0, 0);
            a1 = __builtin_amdgcn_mfma_f32_16x16x32_f16(av, bwf[1][ks], a1, 0, 0, 0);
        }
        #pragma unroll
        for (int reg = 0; reg < 4; ++reg) {
            int j2 = jt * 16 + kg * 4 + reg;
            if (j2 != i) {
                vsum0 += fast_tanh(a0[reg]);
                vsum1 += fast_tanh(a1[reg]);
            }
        }
    }
    vsum0 += __shfl_xor(vsum0, 16); vsum0 += __shfl_xor(vsum0, 32);
    vsum1 += __shfl_xor(vsum1, 16); vsum1 += __shfl_xor(vsum1, 32);
    if (lane < 16) {
        float* Xp = X + (size_t)bi_ * NBB + wave * 32 + lane;
        Xp[0]  += vsum0;
        Xp[16] += vsum1;
    }
}

// ---------------- readout ----------------
__global__ void readoutA_kernel(const int* __restrict__ Z, const float* __restrict__ X,
                                const float* __restrict__ W1, const float* __restrict__ b1,
                                const float* __restrict__ W2, const float* __restrict__ b2,
                                float* __restrict__ yi_buf)
{
    __shared__ float Xs[NBB];
    int bn = blockIdx.x;
    int h = threadIdx.x;      // 0..63
    Xs[h] = X[(size_t)bn * NBB + h];
    Xs[h + 64] = X[(size_t)bn * NBB + h + 64];
    __syncthreads();

    float s = b1[h];
    for (int k = 0; k < NBB; ++k) s += Xs[k] * W1[k * 64 + h];
    float v = tanhf(s) * W2[h];
    #pragma unroll
    for (int off = 32; off > 0; off >>= 1) v += __shfl_down(v, off);
    if (h == 0) {
        int z = Z[bn];
        yi_buf[bn] = (z > 0) ? (v + b2[0]) : 0.f;
    }
}

__global__ void readoutB_kernel(const float* __restrict__ yi_buf, float* __restrict__ y)
{
    int b = blockIdx.x, i = threadIdx.x;
    float v = yi_buf[b * NN + i];
    #pragma unroll
    for (int off = 32; off > 0; off >>= 1) v += __shfl_down(v, off);
    if (i == 0) y[b] = v;
}

extern "C" void kernel_launch(void* const* d_in, const int* in_sizes, int n_in,
                              void* d_out, int out_size, void* d_ws, size_t ws_size,
                              hipStream_t stream) {
    (void)in_sizes; (void)n_in; (void)out_size;
    const int*   Z    = (const int*)d_in[0];
    const float* C    = (const float*)d_in[1];
    const float* Wemb = (const float*)d_in[2];
    const float* Wc   = (const float*)d_in[3];
    const float* bc   = (const float*)d_in[4];
    const float* Wi   = (const float*)d_in[5];
    const float* bi   = (const float*)d_in[6];
    const float* Wf   = (const float*)d_in[7];
    const float* W1   = (const float*)d_in[8];
    const float* b1   = (const float*)d_in[9];
    const float* W2   = (const float*)d_in[10];
    const float* b2   = (const float*)d_in[11];
    float* y = (float*)d_out;

    // ws layout: X f32 | fXh f16 | WcT f16 | WfT f16 | yi f32 | [fCh f16 if it fits]
    char* p = (char*)d_ws;
    float*    X   = (float*)p;              p += (size_t)BB * NN * NBB * 4;
    _Float16* fXh = (_Float16*)p;           p += (size_t)BB * NN * NFF * 2;
    _Float16* WcT = (_Float16*)p;           p += (size_t)NFF * KPAD * 2;
    _Float16* WfT = (_Float16*)p;           p += (size_t)NBB * NFF * 2;
    float*    yi  = (float*)p;              p += (size_t)BB * NN * 4;
    size_t base = (size_t)(p - (char*)d_ws);
    size_t fch_bytes = (size_t)BB * NN * NN * NFF * 2;   // 67 MB
    bool split = (ws_size >= base + fch_bytes);          // constant per session -> deterministic
    _Float16* fCh = (_Float16*)p;

    embed_kernel<<<BB * NN, NBB, 0, stream>>>(Z, Wemb, X);
    transpose_pad_kernel<<<(NFF * KPAD) / 256, 256, 0, stream>>>(Wc, WcT, NGG, KPAD, NFF);
    transpose_pad_kernel<<<(NBB * NFF) / 256, 256, 0, stream>>>(Wf, WfT, NFF, NFF, NBB);

    if (split) {
        fc_kernel<<<BB * NN, 256, 0, stream>>>(Z, C, WcT, bc, fCh);
        for (int it = 0; it < NITER; ++it) {
            fx_kernel<<<BB * NN, NFF, 0, stream>>>(X, Wi, bi, Z, fXh);
            interact_lite<<<BB * NN, 256, 0, stream>>>(Z, fCh, WfT, fXh, X);
        }
    } else {
        for (int it = 0; it < NITER; ++it) {
            fx_kernel<<<BB * NN, NFF, 0, stream>>>(X, Wi, bi, Z, fXh);
            interact_fused<<<BB * NN, 256, 0, stream>>>(Z, C, WcT, bc, WfT, fXh, X);
        }
    }
    readoutA_kernel<<<BB * NN, 64, 0, stream>>>(Z, X, W1, b1, W2, b2, yi);
    readoutB_kernel<<<BB, NN, 0, stream>>>(yi, y);
}

// Round 5
// 160.470 us; speedup vs baseline: 2.2105x; 2.2105x over previous
//
#include <hip/hip_runtime.h>
#include <hip/hip_bf16.h>
#include <math.h>

#define BB   32
#define NN   64
#define NGG  100
#define NBB  128
#define NFF  256
#define NITER 3
#define KPAD 128

typedef _Float16 f16x8 __attribute__((ext_vector_type(8)));
typedef _Float16 f16x4 __attribute__((ext_vector_type(4)));
typedef float    f32x4 __attribute__((ext_vector_type(4)));

static __device__ __forceinline__ float fast_exp2(float x) {
    float r; asm("v_exp_f32 %0, %1" : "=v"(r) : "v"(x)); return r;
}
static __device__ __forceinline__ float fast_rcp(float x) {
    float r; asm("v_rcp_f32 %0, %1" : "=v"(r) : "v"(x)); return r;
}
// tanh(x) = 1 - 2/(e^{2x}+1). Saturates correctly for large |x|.
static __device__ __forceinline__ float fast_tanh(float x) {
    float p = fast_exp2(x * 2.8853900817779268f);
    return 1.0f - 2.0f * fast_rcp(p + 1.0f);
}

// ---------------- embed ----------------
__global__ void embed_kernel(const int* __restrict__ Z, const float* __restrict__ W_emb,
                             float* __restrict__ X) {
    int bn = blockIdx.x, t = threadIdx.x;
    X[bn * NBB + t] = W_emb[Z[bn] * NBB + t];
}

// ---------------- weight prep: fragment layouts ----------------
// WcF[w(4)][ct(4)][ks(4)][lane(64)][e(8)]: lane(l15,kg) holds Wc[k=ks*32+kg*8+e][f=w*64+ct*16+l15]
__global__ void wcfrag_kernel(const float* __restrict__ Wc, _Float16* __restrict__ WcF) {
    int idx = blockIdx.x * 256 + threadIdx.x;   // 32768 total
    int e = idx & 7, lane = (idx >> 3) & 63, ks = (idx >> 9) & 3, ct = (idx >> 11) & 3, w = idx >> 13;
    int l15 = lane & 15, kg = lane >> 4;
    int f = w * 64 + ct * 16 + l15;
    int k = ks * 32 + kg * 8 + e;
    WcF[idx] = (k < NGG) ? (_Float16)Wc[(size_t)k * NFF + f] : (_Float16)0.f;
}
// WfF[w(4)][ct(2)][ks(8)][lane(64)][e(8)]: lane holds Wf[k=ks*32+kg*8+e][o=w*32+ct*16+l15]
__global__ void wffrag_kernel(const float* __restrict__ Wf, _Float16* __restrict__ WfF) {
    int idx = blockIdx.x * 256 + threadIdx.x;   // 32768 total
    int e = idx & 7, lane = (idx >> 3) & 63, ks = (idx >> 9) & 7, ct = (idx >> 12) & 1, w = idx >> 13;
    int l15 = lane & 15, kg = lane >> 4;
    int o = w * 32 + ct * 16 + l15;
    int k = ks * 32 + kg * 8 + e;
    WfF[idx] = (_Float16)Wf[(size_t)k * NBB + o];
}
// old row-major transposed layouts (fused fallback only)
__global__ void transpose_pad_kernel(const float* __restrict__ src, _Float16* __restrict__ dst,
                                     int K, int Kpad, int NC) {
    int idx = blockIdx.x * 256 + threadIdx.x;
    if (idx >= NC * Kpad) return;
    int c = idx / Kpad, k = idx - c * Kpad;
    dst[idx] = (k < K) ? (_Float16)src[(size_t)k * NC + c] : (_Float16)0.f;
}

// ---------------- fX = X @ Wi + bi -> fp16 FRAGMENT layout, Z==0 rows zeroed ----------------
// fXF[b][jt(4)][ks(8)][lane(64)][e(8)]
__global__ void fx_kernel(const float* __restrict__ X, const float* __restrict__ Wi,
                          const float* __restrict__ bi, const int* __restrict__ Z,
                          _Float16* __restrict__ fXF) {
    __shared__ float Xs[NBB];
    int bn = blockIdx.x, t = threadIdx.x;       // t = f
    if (t < NBB) Xs[t] = X[bn * NBB + t];
    __syncthreads();
    float acc = bi[t];
    for (int k = 0; k < NBB; ++k) acc += Xs[k] * Wi[k * NFF + t];
    int b = bn >> 6, jr = bn & 63;
    int jt = jr >> 4, l15 = jr & 15;
    int ks = t >> 5, kg2 = (t >> 3) & 3, e = t & 7;
    size_t off = ((size_t)(b * 32 + jt * 8 + ks) * 64 + (kg2 * 16 + l15)) * 8 + e;
    fXF[off] = (Z[bn] > 0) ? (_Float16)acc : (_Float16)0.f;
}

// ---------------- stage C[b,i] fp32 -> Cs fp16 [64][128] XOR-swizzled ----------------
static __device__ __forceinline__ void stage_C(const float* Crow_base, _Float16* Cs, int t) {
    const int r = t >> 2, q = t & 3;
    const float* Crow = Crow_base + (size_t)r * NGG;
    const int sw = (r & 7) << 3;
    #pragma unroll
    for (int m = 0; m < 8; ++m) {
        const int k = q * 32 + m * 4;
        f16x4 h = {0.f, 0.f, 0.f, 0.f};
        if (k < NGG) {
            float4 v = *(const float4*)(Crow + k);
            h[0] = (_Float16)v.x; h[1] = (_Float16)v.y;
            h[2] = (_Float16)v.z; h[3] = (_Float16)v.w;
        }
        *(f16x4*)&Cs[r * KPAD + (k ^ sw)] = h;
    }
}

// ---------------- fc: fCF[bi][jt][ks][lane][e] = frag of (C[bi,j,:]@Wc + bc), once ----------------
__global__ __launch_bounds__(256, 3) void fc_kernel(
    const int* __restrict__ Z, const float* __restrict__ C,
    const _Float16* __restrict__ WcF, const float* __restrict__ bc,
    _Float16* __restrict__ fCF)
{
    __shared__ __align__(16) _Float16 Cs[NN * KPAD];  // 16 KB
    const int bi_ = blockIdx.x;
    const int b = bi_ >> 6, i = bi_ & 63;
    if (Z[b * NN + i] == 0) return;   // this bi slice never read downstream

    const int t = threadIdx.x;
    const int wave = t >> 6, lane = t & 63;
    const int l15 = lane & 15, kg = lane >> 4;

    stage_C(C + (size_t)bi_ * NN * NGG, Cs, t);

    // A-frags from fragment-layout WcF: contiguous 1KB per (ct,ks)
    f16x8 aw[4][4];
    float4 bcq[4];
    #pragma unroll
    for (int ct = 0; ct < 4; ++ct) {
        #pragma unroll
        for (int ks = 0; ks < 4; ++ks)
            aw[ct][ks] = *(const f16x8*)&WcF[(size_t)(((wave * 4 + ct) * 4 + ks) * 64 + lane) * 8];
        bcq[ct] = *(const float4*)&bc[wave * 64 + ct * 16 + kg * 4];
    }
    __syncthreads();

    #pragma unroll
    for (int jt = 0; jt < 4; ++jt) {
        const int j = jt * 16 + l15;
        const int sw = (l15 & 7) << 3;
        f16x8 bfr[4];
        #pragma unroll
        for (int ks = 0; ks < 4; ++ks)
            bfr[ks] = *(const f16x8*)&Cs[j * KPAD + ((ks * 32 + kg * 8) ^ sw)];
        #pragma unroll
        for (int ct = 0; ct < 4; ++ct) {
            f32x4 acc = {bcq[ct].x, bcq[ct].y, bcq[ct].z, bcq[ct].w};
            #pragma unroll
            for (int ks = 0; ks < 4; ++ks)
                acc = __builtin_amdgcn_mfma_f32_16x16x32_f16(aw[ct][ks], bfr[ks], acc, 0, 0, 0);
            // D: col=l15 (j_local), rows f = wave*64 + ct*16 + kg*4 + reg (4 contiguous halfs)
            const int u = ct * 16 + kg * 4;          // f offset within wave's 64
            const int ksf = wave * 2 + (u >> 5);
            const int kgf = (u >> 3) & 3;
            const int e0 = u & 4;
            f16x4 o;
            o[0] = (_Float16)acc[0]; o[1] = (_Float16)acc[1];
            o[2] = (_Float16)acc[2]; o[3] = (_Float16)acc[3];
            size_t off = ((size_t)(bi_ * 32 + jt * 8 + ksf) * 64 + (kgf * 16 + l15)) * 8 + e0;
            *(f16x4*)&fCF[off] = o;
        }
    }
}

// ---------------- per-pass: fV=fCF⊙fXF (frags) ; pre=fV@Wf ; X += Σ_{j!=i} tanh ----------------
__global__ __launch_bounds__(256, 4) void interact_lite(
    const int* __restrict__ Z, const _Float16* __restrict__ fCF,
    const _Float16* __restrict__ WfF, const _Float16* __restrict__ fXF,
    float* __restrict__ X)
{
    const int bi_ = blockIdx.x;
    const int b = bi_ >> 6, i = bi_ & 63;
    if (Z[b * NN + i] == 0) return;

    const int t = threadIdx.x;
    const int wave = t >> 6, lane = t & 63;
    const int l15 = lane & 15, kg = lane >> 4;

    // B-frags (out-cols [32w,32w+32)): contiguous 1KB loads, register-resident
    f16x8 bwf[2][8];
    #pragma unroll
    for (int ct = 0; ct < 2; ++ct)
        #pragma unroll
        for (int ks = 0; ks < 8; ++ks)
            bwf[ct][ks] = *(const f16x8*)&WfF[(size_t)(((wave * 2 + ct) * 8 + ks) * 64 + lane) * 8];

    const size_t cbase = (size_t)bi_ * 32;
    const size_t xbase = (size_t)b * 32;

    float vsum0 = 0.f, vsum1 = 0.f;
    #pragma unroll
    for (int jt = 0; jt < 4; ++jt) {
        f32x4 a0 = {0.f, 0.f, 0.f, 0.f}, a1 = {0.f, 0.f, 0.f, 0.f};
        #pragma unroll
        for (int ks = 0; ks < 8; ++ks) {
            f16x8 fc = *(const f16x8*)&fCF[((cbase + jt * 8 + ks) * 64 + lane) * 8];
            f16x8 fx = *(const f16x8*)&fXF[((xbase + jt * 8 + ks) * 64 + lane) * 8];
            f16x8 av = fc * fx;                    // v_pk_mul_f16
            a0 = __builtin_amdgcn_mfma_f32_16x16x32_f16(av, bwf[0][ks], a0, 0, 0, 0);
            a1 = __builtin_amdgcn_mfma_f32_16x16x32_f16(av, bwf[1][ks], a1, 0, 0, 0);
        }
        #pragma unroll
        for (int reg = 0; reg < 4; ++reg) {
            int j2 = jt * 16 + kg * 4 + reg;
            if (j2 != i) {
                vsum0 += fast_tanh(a0[reg]);
                vsum1 += fast_tanh(a1[reg]);
            }
        }
    }
    vsum0 += __shfl_xor(vsum0, 16); vsum0 += __shfl_xor(vsum0, 32);
    vsum1 += __shfl_xor(vsum1, 16); vsum1 += __shfl_xor(vsum1, 32);
    if (lane < 16) {
        float* Xp = X + (size_t)bi_ * NBB + wave * 32 + lane;
        Xp[0]  += vsum0;
        Xp[16] += vsum1;
    }
}

// ---------------- fused fallback (old layouts), unchanged structure ----------------
__global__ __launch_bounds__(256, 3) void interact_fused(
    const int* __restrict__ Z, const float* __restrict__ C,
    const _Float16* __restrict__ WcT, const float* __restrict__ bc,
    const _Float16* __restrict__ WfT, const _Float16* __restrict__ fXF,
    float* __restrict__ X)
{
    __shared__ __align__(16) _Float16 Cs[NN * KPAD];
    __shared__ __align__(16) _Float16 fVs[NN * NFF];

    const int bi_ = blockIdx.x;
    const int b = bi_ >> 6, i = bi_ & 63;
    if (Z[b * NN + i] == 0) return;

    const int t = threadIdx.x;
    const int wave = t >> 6, lane = t & 63;
    const int l15 = lane & 15, kg = lane >> 4;

    stage_C(C + (size_t)bi_ * NN * NGG, Cs, t);

    f16x8 aw[4][4];
    float4 bcq[4];
    #pragma unroll
    for (int ct = 0; ct < 4; ++ct) {
        #pragma unroll
        for (int ks = 0; ks < 4; ++ks)
            aw[ct][ks] = *(const f16x8*)&WcT[(size_t)(wave * 64 + ct * 16 + l15) * KPAD + ks * 32 + kg * 8];
        bcq[ct] = *(const float4*)&bc[wave * 64 + ct * 16 + kg * 4];
    }
    __syncthreads();

    #pragma unroll
    for (int jt = 0; jt < 4; ++jt) {
        const int j = jt * 16 + l15;
        const int sw = (l15 & 7) << 3;
        f16x8 bfr[4];
        #pragma unroll
        for (int ks = 0; ks < 4; ++ks)
            bfr[ks] = *(const f16x8*)&Cs[j * KPAD + ((ks * 32 + kg * 8) ^ sw)];
        #pragma unroll
        for (int ct = 0; ct < 4; ++ct) {
            f32x4 acc = {bcq[ct].x, bcq[ct].y, bcq[ct].z, bcq[ct].w};
            #pragma unroll
            for (int ks = 0; ks < 4; ++ks)
                acc = __builtin_amdgcn_mfma_f32_16x16x32_f16(aw[ct][ks], bfr[ks], acc, 0, 0, 0);
            // fXF is fragment layout: f = wave*64+ct*16+kg*4+reg -> (ksf,kgf,e0)
            const int u = ct * 16 + kg * 4;
            const int ksf = wave * 2 + (u >> 5);
            const int kgf = (u >> 3) & 3;
            const int e0 = u & 4;
            f16x4 fx4 = *(const f16x4*)&fXF[((size_t)(b * 32 + jt * 8 + ksf) * 64 + (kgf * 16 + l15)) * 8 + e0];
            const int f0 = wave * 64 + u;
            f16x4 o;
            o[0] = (_Float16)(acc[0] * (float)fx4[0]);
            o[1] = (_Float16)(acc[1] * (float)fx4[1]);
            o[2] = (_Float16)(acc[2] * (float)fx4[2]);
            o[3] = (_Float16)(acc[3] * (float)fx4[3]);
            *(f16x4*)&fVs[j * NFF + (f0 ^ ((j & 7) << 3))] = o;
        }
    }
    __syncthreads();

    f16x8 bwf[2][8];
    #pragma unroll
    for (int ct = 0; ct < 2; ++ct)
        #pragma unroll
        for (int ks = 0; ks < 8; ++ks)
            bwf[ct][ks] = *(const f16x8*)&WfT[(size_t)(wave * 32 + ct * 16 + l15) * NFF + ks * 32 + kg * 8];

    float vsum0 = 0.f, vsum1 = 0.f;
    #pragma unroll
    for (int jt = 0; jt < 4; ++jt) {
        const int r = jt * 16 + l15;
        const int sw = (l15 & 7) << 3;
        f32x4 a0 = {0.f, 0.f, 0.f, 0.f}, a1 = {0.f, 0.f, 0.f, 0.f};
        #pragma unroll
        for (int ks = 0; ks < 8; ++ks) {
            f16x8 av = *(const f16x8*)&fVs[r * NFF + ((ks * 32 + kg * 8) ^ sw)];
            a0 = __builtin_amdgcn_mfma_f32_16x16x32_f16(av, bwf[0][ks], a0, 0, 0, 0);
            a1 = __builtin_amdgcn_mfma_f32_16x16x32_f16(av, bwf[1][ks], a1, 0, 0, 0);
        }
        #pragma unroll
        for (int reg = 0; reg < 4; ++reg) {
            int j2 = jt * 16 + kg * 4 + reg;
            if (j2 != i) {
                vsum0 += fast_tanh(a0[reg]);
                vsum1 += fast_tanh(a1[reg]);
            }
        }
    }
    vsum0 += __shfl_xor(vsum0, 16); vsum0 += __shfl_xor(vsum0, 32);
    vsum1 += __shfl_xor(vsum1, 16); vsum1 += __shfl_xor(vsum1, 32);
    if (lane < 16) {
        float* Xp = X + (size_t)bi_ * NBB + wave * 32 + lane;
        Xp[0]  += vsum0;
        Xp[16] += vsum1;
    }
}

// ---------------- readout ----------------
__global__ void readoutA_kernel(const int* __restrict__ Z, const float* __restrict__ X,
                                const float* __restrict__ W1, const float* __restrict__ b1,
                                const float* __restrict__ W2, const float* __restrict__ b2,
                                float* __restrict__ yi_buf)
{
    __shared__ float Xs[NBB];
    int bn = blockIdx.x;
    int h = threadIdx.x;
    Xs[h] = X[(size_t)bn * NBB + h];
    Xs[h + 64] = X[(size_t)bn * NBB + h + 64];
    __syncthreads();

    float s = b1[h];
    for (int k = 0; k < NBB; ++k) s += Xs[k] * W1[k * 64 + h];
    float v = tanhf(s) * W2[h];
    #pragma unroll
    for (int off = 32; off > 0; off >>= 1) v += __shfl_down(v, off);
    if (h == 0) {
        int z = Z[bn];
        yi_buf[bn] = (z > 0) ? (v + b2[0]) : 0.f;
    }
}

__global__ void readoutB_kernel(const float* __restrict__ yi_buf, float* __restrict__ y)
{
    int b = blockIdx.x, i = threadIdx.x;
    float v = yi_buf[b * NN + i];
    #pragma unroll
    for (int off = 32; off > 0; off >>= 1) v += __shfl_down(v, off);
    if (i == 0) y[b] = v;
}

extern "C" void kernel_launch(void* const* d_in, const int* in_sizes, int n_in,
                              void* d_out, int out_size, void* d_ws, size_t ws_size,
                              hipStream_t stream) {
    (void)in_sizes; (void)n_in; (void)out_size;
    const int*   Z    = (const int*)d_in[0];
    const float* C    = (const float*)d_in[1];
    const float* Wemb = (const float*)d_in[2];
    const float* Wc   = (const float*)d_in[3];
    const float* bc   = (const float*)d_in[4];
    const float* Wi   = (const float*)d_in[5];
    const float* bi   = (const float*)d_in[6];
    const float* Wf   = (const float*)d_in[7];
    const float* W1   = (const float*)d_in[8];
    const float* b1   = (const float*)d_in[9];
    const float* W2   = (const float*)d_in[10];
    const float* b2   = (const float*)d_in[11];
    float* y = (float*)d_out;

    // ws: X f32 | fXF f16 | WcF f16 | WfF f16 | WcT f16 | WfT f16 | yi f32 | fCF f16(67MB)
    char* p = (char*)d_ws;
    float*    X   = (float*)p;      p += (size_t)BB * NN * NBB * 4;
    _Float16* fXF = (_Float16*)p;   p += (size_t)BB * NN * NFF * 2;
    _Float16* WcF = (_Float16*)p;   p += (size_t)NFF * KPAD * 2;
    _Float16* WfF = (_Float16*)p;   p += (size_t)NBB * NFF * 2;
    _Float16* WcT = (_Float16*)p;   p += (size_t)NFF * KPAD * 2;
    _Float16* WfT = (_Float16*)p;   p += (size_t)NBB * NFF * 2;
    float*    yi  = (float*)p;      p += (size_t)BB * NN * 4;
    size_t base = (size_t)(p - (char*)d_ws);
    size_t fcf_bytes = (size_t)BB * NN * NN * NFF * 2;   // 67 MB
    bool split = (ws_size >= base + fcf_bytes);          // constant per session
    _Float16* fCF = (_Float16*)p;

    embed_kernel<<<BB * NN, NBB, 0, stream>>>(Z, Wemb, X);

    if (split) {
        wcfrag_kernel<<<(NFF * KPAD) / 256, 256, 0, stream>>>(Wc, WcF);
        wffrag_kernel<<<(NBB * NFF) / 256, 256, 0, stream>>>(Wf, WfF);
        fc_kernel<<<BB * NN, 256, 0, stream>>>(Z, C, WcF, bc, fCF);
        for (int it = 0; it < NITER; ++it) {
            fx_kernel<<<BB * NN, NFF, 0, stream>>>(X, Wi, bi, Z, fXF);
            interact_lite<<<BB * NN, 256, 0, stream>>>(Z, fCF, WfF, fXF, X);
        }
    } else {
        transpose_pad_kernel<<<(NFF * KPAD) / 256, 256, 0, stream>>>(Wc, WcT, NGG, KPAD, NFF);
        transpose_pad_kernel<<<(NBB * NFF) / 256, 256, 0, stream>>>(Wf, WfT, NFF, NFF, NBB);
        for (int it = 0; it < NITER; ++it) {
            fx_kernel<<<BB * NN, NFF, 0, stream>>>(X, Wi, bi, Z, fXF);
            interact_fused<<<BB * NN, 256, 0, stream>>>(Z, C, WcT, bc, WfT, fXF, X);
        }
    }
    readoutA_kernel<<<BB * NN, 64, 0, stream>>>(Z, X, W1, b1, W2, b2, yi);
    readoutB_kernel<<<BB, NN, 0, stream>>>(yi, y);
}